// Round 7
// baseline (341.556 us; speedup 1.0000x reference)
//
#include <hip/hip_runtime.h>
#include <math.h>
#include <stdint.h>

#define D_MODEL 1024
#define N_HEADS 16
#define HEAD_DIM 64
#define BATCH 2
#define SEQ 2048
#define TOKENS (BATCH * SEQ)   // 4096

typedef __attribute__((ext_vector_type(8))) short short8;   // 8 bf16 = 4 VGPRs
typedef __attribute__((ext_vector_type(4))) float floatx4;  // MFMA C/D frag

#define BMFMA(a, b, c) __builtin_amdgcn_mfma_f32_16x16x32_bf16(a, b, c, 0, 0, 0)

__device__ __forceinline__ unsigned short f2bf(float f) {
    uint32_t u = __float_as_uint(f);
    u += 0x7fffu + ((u >> 16) & 1u);
    return (unsigned short)(u >> 16);
}
__device__ __forceinline__ float bf2f(unsigned short h) {
    return __uint_as_float(((uint32_t)h) << 16);
}

// async global -> LDS, 16B per lane; LDS dest = wave-uniform base + lane*16
#define GLD_LDS16(gp, lp) __builtin_amdgcn_global_load_lds(                 \
    (const __attribute__((address_space(1))) void*)(gp),                    \
    (__attribute__((address_space(3))) void*)(lp), 16, 0, 0)

// ---------------------------------------------------------------------------
// split_a: X fp32 [rows][1024] -> Ax bf16 [rows][2048] (hi | lo along k)
// ---------------------------------------------------------------------------
__global__ __launch_bounds__(256) void split_a(
    const float* __restrict__ X, unsigned short* __restrict__ Ax)
{
    const int idx = blockIdx.x * 256 + threadIdx.x;
    const int row = idx >> 8;            // 256 threads cover one 1024-row
    const int c = (idx & 255) * 4;
    float4 v = *(const float4*)(X + (size_t)row * 1024 + c);
    float f[4] = {v.x, v.y, v.z, v.w};
    uint32_t hp[2], lp[2];
#pragma unroll
    for (int j = 0; j < 2; ++j) {
        unsigned short h0 = f2bf(f[2 * j]), h1 = f2bf(f[2 * j + 1]);
        hp[j] = (uint32_t)h0 | ((uint32_t)h1 << 16);
        lp[j] = (uint32_t)f2bf(f[2 * j] - bf2f(h0)) |
                ((uint32_t)f2bf(f[2 * j + 1] - bf2f(h1)) << 16);
    }
    *(uint2*)(Ax + (size_t)row * 2048 + c) = make_uint2(hp[0], hp[1]);
    *(uint2*)(Ax + (size_t)row * 2048 + 1024 + c) = make_uint2(lp[0], lp[1]);
}

// ---------------------------------------------------------------------------
// Weight transpose + bf16 hi/lo split (unchanged, passing)
// ---------------------------------------------------------------------------
__global__ __launch_bounds__(256) void split_w_t(
    const float* __restrict__ W, int N, unsigned short* __restrict__ Bt)
{
    __shared__ float t[32][33];
    const int tid = threadIdx.x;
    const int n0 = blockIdx.x * 32, k0 = blockIdx.y * 32;
    const int c = tid & 31, r = tid >> 5;
#pragma unroll
    for (int i = 0; i < 4; ++i)
        t[r + 8 * i][c] = W[(size_t)(k0 + r + 8 * i) * N + n0 + c];
    __syncthreads();
#pragma unroll
    for (int i = 0; i < 4; ++i) {
        int dn = r + 8 * i;
        float f = t[c][dn];
        unsigned short hi = f2bf(f);
        unsigned short lo = f2bf(f - bf2f(hi));
        size_t row = (size_t)(n0 + dn) * 2048;
        Bt[row + k0 + c] = hi;
        Bt[row + 1024 + k0 + c] = lo;
    }
}

// ---------------------------------------------------------------------------
// FUSED x3 bf16 MFMA GEMM (unchanged from R6, passing)
// ---------------------------------------------------------------------------
template<int WM, int WN, int FM, int FN>
__global__ __launch_bounds__(256) void gemm_mfma_x3f(
    const unsigned short* __restrict__ Ax, const unsigned short* __restrict__ Bt,
    const float* __restrict__ bias, float* __restrict__ C, int M, int N)
{
    constexpr int BM = WM * FM * 16;
    constexpr int BN = WN * FN * 16;
    constexpr int NA = BM / 64;
    constexpr int NB = BN / 64;

    __shared__ __align__(16) unsigned short sAh[BM * 32];
    __shared__ __align__(16) unsigned short sAl[BM * 32];
    __shared__ __align__(16) unsigned short sBh[BN * 32];
    __shared__ __align__(16) unsigned short sBl[BN * 32];

    const int tid = threadIdx.x;
    const int w = tid >> 6, lane = tid & 63;
    const int l15 = lane & 15, quad = lane >> 4;
    const int wm = w / WN, wn = w % WN;
    const int m0 = blockIdx.y * BM, n0 = blockIdx.x * BN;

    const int ch = (lane & 3) ^ ((lane >> 3) & 3);       // staging swizzle
    const int sw = (quad ^ ((l15 >> 1) & 3)) * 8;        // frag-read swizzle

    const unsigned short* aG[NA];
    const unsigned short* bG[NB];
#pragma unroll
    for (int i = 0; i < NA; ++i)
        aG[i] = Ax + (size_t)(m0 + (w * NA + i) * 16 + (lane >> 2)) * 2048
                   + ch * 8;
#pragma unroll
    for (int i = 0; i < NB; ++i)
        bG[i] = Bt + (size_t)(n0 + (w * NB + i) * 16 + (lane >> 2)) * 2048
                   + ch * 8;

    floatx4 acc[FM][FN];
#pragma unroll
    for (int fm = 0; fm < FM; ++fm)
#pragma unroll
        for (int fn = 0; fn < FN; ++fn) acc[fm][fn] = (floatx4)0.f;

    for (int ks = 0; ks < 32; ++ks) {
        const int ko = ks * 32;          // hi at ko, lo at 1024+ko
        __syncthreads();
#pragma unroll
        for (int i = 0; i < NA; ++i) {
            GLD_LDS16(aG[i] + ko,        sAh + (w * NA + i) * 512);
            GLD_LDS16(aG[i] + 1024 + ko, sAl + (w * NA + i) * 512);
        }
#pragma unroll
        for (int i = 0; i < NB; ++i) {
            GLD_LDS16(bG[i] + ko,        sBh + (w * NB + i) * 512);
            GLD_LDS16(bG[i] + 1024 + ko, sBl + (w * NB + i) * 512);
        }
        __syncthreads();

        short8 ah[FM], al[FM], bh[FN], bl[FN];
#pragma unroll
        for (int fm = 0; fm < FM; ++fm) {
            const int off = ((wm * FM + fm) * 16 + l15) * 32 + sw;
            ah[fm] = *(const short8*)&sAh[off];
            al[fm] = *(const short8*)&sAl[off];
        }
#pragma unroll
        for (int fn = 0; fn < FN; ++fn) {
            const int off = ((wn * FN + fn) * 16 + l15) * 32 + sw;
            bh[fn] = *(const short8*)&sBh[off];
            bl[fn] = *(const short8*)&sBl[off];
        }
#pragma unroll
        for (int fm = 0; fm < FM; ++fm)
#pragma unroll
            for (int fn = 0; fn < FN; ++fn) {
                floatx4 a = acc[fm][fn];
                a = BMFMA(ah[fm], bh[fn], a);
                a = BMFMA(ah[fm], bl[fn], a);
                a = BMFMA(al[fm], bh[fn], a);
                acc[fm][fn] = a;
            }
    }

#pragma unroll
    for (int fm = 0; fm < FM; ++fm)
#pragma unroll
        for (int fn = 0; fn < FN; ++fn) {
            int col = n0 + (wn * FN + fn) * 16 + l15;
            float bv = bias[col];
#pragma unroll
            for (int r = 0; r < 4; ++r) {
                int row = m0 + (wm * FM + fm) * 16 + quad * 4 + r;
                C[(size_t)row * N + col] = acc[fm][fn][r] + bv;
            }
        }
}

// ---------------------------------------------------------------------------
// prep_qkv (unchanged, passing): RoPE + 1/8 q-scale + bf16 hi/lo split,
// Q/K: [bh][t][64], V: [bh][d][2048] transposed.
// ---------------------------------------------------------------------------
__global__ __launch_bounds__(256) void prep_qkv(
    const float* __restrict__ qkv,
    unsigned short* __restrict__ Qh, unsigned short* __restrict__ Ql,
    unsigned short* __restrict__ Kh, unsigned short* __restrict__ Kl,
    unsigned short* __restrict__ Vh, unsigned short* __restrict__ Vl)
{
    __shared__ float vt[64][65];
    const int tid = threadIdx.x;
    const int lin = blockIdx.x;
    const int tt = lin & 31, bh = lin >> 5;
    const int b = bh >> 4, h = bh & 15;
    const int r = tid >> 2;
    const int dblk = (tid & 3) * 16;
    const int tg = tt * 64 + r;
    const size_t src = (size_t)(b * SEQ + tg) * 3072 + h * 64 + dblk;
    const size_t dst = ((size_t)bh * SEQ + tg) * 64 + dblk;

    float q[16], k[16], v[16];
#pragma unroll
    for (int i = 0; i < 4; ++i) {
        *(float4*)&q[4 * i] = *(const float4*)(qkv + src + 4 * i);
        *(float4*)&k[4 * i] = *(const float4*)(qkv + src + 1024 + 4 * i);
        *(float4*)&v[4 * i] = *(const float4*)(qkv + src + 2048 + 4 * i);
    }
#pragma unroll
    for (int j = 0; j < 16; j += 2) {
        int pr = (dblk + j) >> 1;
        double e = (double)(2 * pr) / 64.0;
        float inv = (float)exp2(-e * 13.287712379549449);
        float ang = (float)tg * inv;
        float s, c;
        __sincosf(ang, &s, &c);
        float qe = q[j], qo = q[j + 1];
        q[j] = qe * c - qo * s; q[j + 1] = qe * s + qo * c;
        float ke = k[j], ko = k[j + 1];
        k[j] = ke * c - ko * s; k[j + 1] = ke * s + ko * c;
    }
    uint32_t ph[8], pl[8];
#pragma unroll
    for (int j = 0; j < 8; ++j) {
        float f0 = q[2 * j] * 0.125f, f1 = q[2 * j + 1] * 0.125f;
        unsigned short h0 = f2bf(f0), h1 = f2bf(f1);
        ph[j] = (uint32_t)h0 | ((uint32_t)h1 << 16);
        pl[j] = (uint32_t)f2bf(f0 - bf2f(h0)) | ((uint32_t)f2bf(f1 - bf2f(h1)) << 16);
    }
    *(uint4*)(Qh + dst) = *(uint4*)&ph[0]; *(uint4*)(Qh + dst + 8) = *(uint4*)&ph[4];
    *(uint4*)(Ql + dst) = *(uint4*)&pl[0]; *(uint4*)(Ql + dst + 8) = *(uint4*)&pl[4];
#pragma unroll
    for (int j = 0; j < 8; ++j) {
        float f0 = k[2 * j], f1 = k[2 * j + 1];
        unsigned short h0 = f2bf(f0), h1 = f2bf(f1);
        ph[j] = (uint32_t)h0 | ((uint32_t)h1 << 16);
        pl[j] = (uint32_t)f2bf(f0 - bf2f(h0)) | ((uint32_t)f2bf(f1 - bf2f(h1)) << 16);
    }
    *(uint4*)(Kh + dst) = *(uint4*)&ph[0]; *(uint4*)(Kh + dst + 8) = *(uint4*)&ph[4];
    *(uint4*)(Kl + dst) = *(uint4*)&pl[0]; *(uint4*)(Kl + dst + 8) = *(uint4*)&pl[4];

#pragma unroll
    for (int j = 0; j < 16; ++j) vt[r][dblk + j] = v[j];
    __syncthreads();
    const int d2 = tid >> 2;
    const int tb = (tid & 3) * 16;
#pragma unroll
    for (int j = 0; j < 8; ++j) {
        float f0 = vt[tb + 2 * j][d2], f1 = vt[tb + 2 * j + 1][d2];
        unsigned short h0 = f2bf(f0), h1 = f2bf(f1);
        ph[j] = (uint32_t)h0 | ((uint32_t)h1 << 16);
        pl[j] = (uint32_t)f2bf(f0 - bf2f(h0)) | ((uint32_t)f2bf(f1 - bf2f(h1)) << 16);
    }
    const size_t vdst = ((size_t)bh * 64 + d2) * SEQ + tt * 64 + tb;
    *(uint4*)(Vh + vdst) = *(uint4*)&ph[0]; *(uint4*)(Vh + vdst + 8) = *(uint4*)&ph[4];
    *(uint4*)(Vl + vdst) = *(uint4*)&pl[0]; *(uint4*)(Vl + vdst + 8) = *(uint4*)&pl[4];
}

// ---------------------------------------------------------------------------
// MFMA flash attention, R7: fixed-shift softmax (no running max/rescale),
// S^T via swapped MFMA operands (P staging = 4 conflict-free ds_write_b64),
// l via ones-MFMA, GEMM-style [row][32] XOR-swizzled LDS (0 conflicts).
// LDS 40KB -> 4 blocks/CU. Block = q-tile pair {p, 31-p}: 33 iters, balanced.
// ---------------------------------------------------------------------------
__global__ __launch_bounds__(256, 2) void flash_mfma(
    const unsigned short* __restrict__ Qh, const unsigned short* __restrict__ Ql,
    const unsigned short* __restrict__ Kh, const unsigned short* __restrict__ Kl,
    const unsigned short* __restrict__ Vh, const unsigned short* __restrict__ Vl,
    const int* __restrict__ am, unsigned short* __restrict__ attnx)
{
    // layout: [d-half (t-half for V)] [row 0..63] [32 shorts, XOR-swizzled]
    __shared__ __align__(16) unsigned short sKh[4096];
    __shared__ __align__(16) unsigned short sKl[4096];
    __shared__ __align__(16) unsigned short sVh[4096];
    __shared__ __align__(16) unsigned short sVl[4096];
    __shared__ __align__(16) unsigned short sP[4096];    // 4 waves x [2][16][32]

    const int tid = threadIdx.x;
    const int lane = tid & 63, w = tid >> 6;
    const int l15 = lane & 15, quad = lane >> 4;
    const int lin = blockIdx.x;
    const int bh = lin & 31;
    const int p = lin >> 5;
    const int b = bh >> 4, h = bh & 15;
    const int sw = (quad ^ ((l15 >> 1) & 3)) * 8;        // frag-read swizzle
    unsigned short* pbase = sP + w * 1024;

    short8 ones;
#pragma unroll
    for (int j = 0; j < 8; ++j) ones[j] = (short)0x3F80;  // bf16 1.0

#pragma unroll
    for (int phase = 0; phase < 2; ++phase) {
        const int qt = phase ? (31 - p) : p;

        const size_t qb = ((size_t)bh * SEQ + qt * 64 + w * 16 + l15) * 64 + quad * 8;
        const short8 qh0 = *(const short8*)(Qh + qb);
        const short8 qh1 = *(const short8*)(Qh + qb + 32);
        const short8 ql0 = *(const short8*)(Ql + qb);
        const short8 ql1 = *(const short8*)(Ql + qb + 32);

        floatx4 O[4];
        floatx4 lAcc = (floatx4)0.f;
#pragma unroll
        for (int nf = 0; nf < 4; ++nf) O[nf] = (floatx4)0.f;

        const int mg = qt * 64 + w * 16 + l15;           // this lane's q-row

        for (int kt = 0; kt <= qt; ++kt) {
            __syncthreads();   // all waves done reading previous K/V tiles
#pragma unroll
            for (int i = 0; i < 2; ++i) {
                const int u = tid + i * 256;
                const int row = u >> 3, blk = u & 7;
                const int half = blk >> 2, c = blk & 3;
                const int lofs = half * 2048 + row * 32 + (c ^ ((row >> 1) & 3)) * 8;
                const size_t kg = ((size_t)bh * SEQ + kt * 64 + row) * 64 + blk * 8;
                const size_t vg = ((size_t)bh * 64 + row) * SEQ + kt * 64 + blk * 8;
                *(uint4*)&sKh[lofs] = *(const uint4*)(Kh + kg);
                *(uint4*)&sKl[lofs] = *(const uint4*)(Kl + kg);
                *(uint4*)&sVh[lofs] = *(const uint4*)(Vh + vg);
                *(uint4*)&sVl[lofs] = *(const uint4*)(Vl + vg);
            }
            __syncthreads();

            const bool diag = (kt == qt);

            // ---- S^T = K Q^T (x3), exp, pack, stage P (wave-private) ----
#pragma unroll
            for (int nf = 0; nf < 4; ++nf) {
                const int base = (nf * 16 + l15) * 32 + sw;
                const short8 kh0 = *(const short8*)&sKh[base];
                const short8 kh1 = *(const short8*)&sKh[2048 + base];
                const short8 kl0 = *(const short8*)&sKl[base];
                const short8 kl1 = *(const short8*)&sKl[2048 + base];
                floatx4 s = (floatx4)0.f;
                s = BMFMA(kh0, qh0, s);
                s = BMFMA(kh1, qh1, s);
                s = BMFMA(kl0, qh0, s);
                s = BMFMA(kl1, qh1, s);
                s = BMFMA(kh0, ql0, s);
                s = BMFMA(kh1, ql1, s);

                const int tb = kt * 64 + nf * 16 + quad * 4;
                const int4 amv = *(const int4*)(am + b * SEQ + tb);
                float pv[4];
#pragma unroll
                for (int r = 0; r < 4; ++r) {
                    bool ok = ((const int*)&amv)[r] != 0;
                    if (diag) ok = ok && (tb + r <= mg);
                    pv[r] = ok ? __expf(s[r] - 16.0f) : 0.0f;
                }
                ushort4 pk;
                pk.x = f2bf(pv[0]); pk.y = f2bf(pv[1]);
                pk.z = f2bf(pv[2]); pk.w = f2bf(pv[3]);
                const int pos = (((nf & 1) * 2 + (quad >> 1)) ^ ((l15 >> 1) & 3));
                *(ushort4*)(pbase + (nf >> 1) * 512 + l15 * 32 + pos * 8
                            + (quad & 1) * 4) = pk;
            }

            // ---- read P fragments (same-wave RAW: lgkmcnt only) ----
            const short8 pf0 = *(const short8*)(pbase + l15 * 32 + sw);
            const short8 pf1 = *(const short8*)(pbase + 512 + l15 * 32 + sw);

            // ---- l += P @ ones ; O += P @ (Vh + Vl) ----
            lAcc = BMFMA(pf0, ones, lAcc);
            lAcc = BMFMA(pf1, ones, lAcc);
#pragma unroll
            for (int nf = 0; nf < 4; ++nf) {
                const int vb = (nf * 16 + l15) * 32 + sw;
                floatx4 o = O[nf];
                o = BMFMA(pf0, *(const short8*)&sVh[vb], o);
                o = BMFMA(pf1, *(const short8*)&sVh[2048 + vb], o);
                o = BMFMA(pf0, *(const short8*)&sVl[vb], o);
                o = BMFMA(pf1, *(const short8*)&sVl[2048 + vb], o);
                O[nf] = o;
            }
        }

        // ---- finalize: divide by l, store bf16 hi|lo ----
        float rl[4];
#pragma unroll
        for (int r = 0; r < 4; ++r) rl[r] = 1.0f / lAcc[r];
#pragma unroll
        for (int nf = 0; nf < 4; ++nf)
#pragma unroll
            for (int r = 0; r < 4; ++r) {
                const int tok = b * SEQ + qt * 64 + w * 16 + quad * 4 + r;
                const int col = h * 64 + nf * 16 + l15;
                const float val = O[nf][r] * rl[r];
                const unsigned short hi = f2bf(val);
                const unsigned short lo = f2bf(val - bf2f(hi));
                attnx[(size_t)tok * 2048 + col] = hi;
                attnx[(size_t)tok * 2048 + 1024 + col] = lo;
            }
    }
}

// ---------------------------------------------------------------------------
extern "C" void kernel_launch(void* const* d_in, const int* in_sizes, int n_in,
                              void* d_out, int out_size, void* d_ws, size_t ws_size,
                              hipStream_t stream)
{
    const float* x    = (const float*)d_in[0];
    const int*   am   = (const int*)d_in[1];
    const float* Wqkv = (const float*)d_in[2];
    const float* bqkv = (const float*)d_in[3];
    const float* Wout = (const float*)d_in[4];
    const float* bout = (const float*)d_in[5];
    float* out = (float*)d_out;

    // ws layout (113.2 MB, unchanged):
    //   Bt 12.58MB | qkv fp32 50.33MB (reused as attnx bf16 after prep) |
    //   Qh Ql Kh Kl Vh Vl 8.39MB each (Vh+Vl doubles as Ax before prep)
    char* ws = (char*)d_ws;
    unsigned short* Bt = (unsigned short*)ws;
    float* qkv = (float*)(ws + 12582912);
    unsigned short* attnx = (unsigned short*)qkv;        // alias: qkv dead after prep
    unsigned short* Qh = (unsigned short*)(ws + 62914560);
    unsigned short* Ql = Qh + 4194304;
    unsigned short* Kh = Ql + 4194304;
    unsigned short* Kl = Kh + 4194304;
    unsigned short* Vh = Kl + 4194304;
    unsigned short* Vl = Vh + 4194304;
    unsigned short* Ax = Vh;                             // alias: dead after gemm1

    // 0) split x -> bf16 hi|lo
    split_a<<<4096, 256, 0, stream>>>(x, Ax);

    // 1) qkv = x @ W_qkv + b   (fused-x3 bf16 MFMA, swizzled LDS, DMA staging)
    split_w_t<<<dim3(96, 32), 256, 0, stream>>>(Wqkv, 3072, Bt);
    gemm_mfma_x3f<2, 2, 4, 4><<<dim3(24, 32), 256, 0, stream>>>(
        Ax, Bt, bqkv, qkv, TOKENS, 3072);

    // 2) RoPE + scale + split + V transpose (overwrites Ax region - ordered)
    prep_qkv<<<1024, 256, 0, stream>>>(qkv, Qh, Ql, Kh, Kl, Vh, Vl);

    // 3) MFMA flash attention -> attnx (bf16 hi|lo, into dead qkv region)
    flash_mfma<<<512, 256, 0, stream>>>(Qh, Ql, Kh, Kl, Vh, Vl, am, attnx);

    // 4) out = attn @ W_out + b
    split_w_t<<<dim3(32, 32), 256, 0, stream>>>(Wout, 1024, Bt);
    gemm_mfma_x3f<2, 2, 2, 4><<<dim3(8, 64), 256, 0, stream>>>(
        attnx, Bt, bout, out, TOKENS, 1024);
}

// Round 8
// 322.237 us; speedup vs baseline: 1.0600x; 1.0600x over previous
//
#include <hip/hip_runtime.h>
#include <math.h>
#include <stdint.h>

#define D_MODEL 1024
#define N_HEADS 16
#define HEAD_DIM 64
#define BATCH 2
#define SEQ 2048
#define TOKENS (BATCH * SEQ)   // 4096

typedef __attribute__((ext_vector_type(8))) short short8;   // 8 bf16 = 4 VGPRs
typedef __attribute__((ext_vector_type(4))) float floatx4;  // MFMA C/D frag

#define BMFMA(a, b, c) __builtin_amdgcn_mfma_f32_16x16x32_bf16(a, b, c, 0, 0, 0)

__device__ __forceinline__ unsigned short f2bf(float f) {
    uint32_t u = __float_as_uint(f);
    u += 0x7fffu + ((u >> 16) & 1u);
    return (unsigned short)(u >> 16);
}
__device__ __forceinline__ float bf2f(unsigned short h) {
    return __uint_as_float(((uint32_t)h) << 16);
}

// async global -> LDS, 16B per lane; LDS dest = wave-uniform base + lane*16
#define GLD_LDS16(gp, lp) __builtin_amdgcn_global_load_lds(                 \
    (const __attribute__((address_space(1))) void*)(gp),                    \
    (__attribute__((address_space(3))) void*)(lp), 16, 0, 0)

// ---------------------------------------------------------------------------
// split_a: X fp32 [rows][1024] -> Ax bf16 [rows][2048] (hi | lo along k)
// ---------------------------------------------------------------------------
__global__ __launch_bounds__(256) void split_a(
    const float* __restrict__ X, unsigned short* __restrict__ Ax)
{
    const int idx = blockIdx.x * 256 + threadIdx.x;
    const int row = idx >> 8;            // 256 threads cover one 1024-row
    const int c = (idx & 255) * 4;
    float4 v = *(const float4*)(X + (size_t)row * 1024 + c);
    float f[4] = {v.x, v.y, v.z, v.w};
    uint32_t hp[2], lp[2];
#pragma unroll
    for (int j = 0; j < 2; ++j) {
        unsigned short h0 = f2bf(f[2 * j]), h1 = f2bf(f[2 * j + 1]);
        hp[j] = (uint32_t)h0 | ((uint32_t)h1 << 16);
        lp[j] = (uint32_t)f2bf(f[2 * j] - bf2f(h0)) |
                ((uint32_t)f2bf(f[2 * j + 1] - bf2f(h1)) << 16);
    }
    *(uint2*)(Ax + (size_t)row * 2048 + c) = make_uint2(hp[0], hp[1]);
    *(uint2*)(Ax + (size_t)row * 2048 + 1024 + c) = make_uint2(lp[0], lp[1]);
}

// ---------------------------------------------------------------------------
// Weight transpose + bf16 hi/lo split (unchanged, passing)
// ---------------------------------------------------------------------------
__global__ __launch_bounds__(256) void split_w_t(
    const float* __restrict__ W, int N, unsigned short* __restrict__ Bt)
{
    __shared__ float t[32][33];
    const int tid = threadIdx.x;
    const int n0 = blockIdx.x * 32, k0 = blockIdx.y * 32;
    const int c = tid & 31, r = tid >> 5;
#pragma unroll
    for (int i = 0; i < 4; ++i)
        t[r + 8 * i][c] = W[(size_t)(k0 + r + 8 * i) * N + n0 + c];
    __syncthreads();
#pragma unroll
    for (int i = 0; i < 4; ++i) {
        int dn = r + 8 * i;
        float f = t[c][dn];
        unsigned short hi = f2bf(f);
        unsigned short lo = f2bf(f - bf2f(hi));
        size_t row = (size_t)(n0 + dn) * 2048;
        Bt[row + k0 + c] = hi;
        Bt[row + 1024 + k0 + c] = lo;
    }
}

// ---------------------------------------------------------------------------
// FUSED x3 bf16 MFMA GEMM (unchanged from R6, passing)
// ---------------------------------------------------------------------------
template<int WM, int WN, int FM, int FN>
__global__ __launch_bounds__(256) void gemm_mfma_x3f(
    const unsigned short* __restrict__ Ax, const unsigned short* __restrict__ Bt,
    const float* __restrict__ bias, float* __restrict__ C, int M, int N)
{
    constexpr int BM = WM * FM * 16;
    constexpr int BN = WN * FN * 16;
    constexpr int NA = BM / 64;
    constexpr int NB = BN / 64;

    __shared__ __align__(16) unsigned short sAh[BM * 32];
    __shared__ __align__(16) unsigned short sAl[BM * 32];
    __shared__ __align__(16) unsigned short sBh[BN * 32];
    __shared__ __align__(16) unsigned short sBl[BN * 32];

    const int tid = threadIdx.x;
    const int w = tid >> 6, lane = tid & 63;
    const int l15 = lane & 15, quad = lane >> 4;
    const int wm = w / WN, wn = w % WN;
    const int m0 = blockIdx.y * BM, n0 = blockIdx.x * BN;

    const int ch = (lane & 3) ^ ((lane >> 3) & 3);       // staging swizzle
    const int sw = (quad ^ ((l15 >> 1) & 3)) * 8;        // frag-read swizzle

    const unsigned short* aG[NA];
    const unsigned short* bG[NB];
#pragma unroll
    for (int i = 0; i < NA; ++i)
        aG[i] = Ax + (size_t)(m0 + (w * NA + i) * 16 + (lane >> 2)) * 2048
                   + ch * 8;
#pragma unroll
    for (int i = 0; i < NB; ++i)
        bG[i] = Bt + (size_t)(n0 + (w * NB + i) * 16 + (lane >> 2)) * 2048
                   + ch * 8;

    floatx4 acc[FM][FN];
#pragma unroll
    for (int fm = 0; fm < FM; ++fm)
#pragma unroll
        for (int fn = 0; fn < FN; ++fn) acc[fm][fn] = (floatx4)0.f;

    for (int ks = 0; ks < 32; ++ks) {
        const int ko = ks * 32;          // hi at ko, lo at 1024+ko
        __syncthreads();
#pragma unroll
        for (int i = 0; i < NA; ++i) {
            GLD_LDS16(aG[i] + ko,        sAh + (w * NA + i) * 512);
            GLD_LDS16(aG[i] + 1024 + ko, sAl + (w * NA + i) * 512);
        }
#pragma unroll
        for (int i = 0; i < NB; ++i) {
            GLD_LDS16(bG[i] + ko,        sBh + (w * NB + i) * 512);
            GLD_LDS16(bG[i] + 1024 + ko, sBl + (w * NB + i) * 512);
        }
        __syncthreads();

        short8 ah[FM], al[FM], bh[FN], bl[FN];
#pragma unroll
        for (int fm = 0; fm < FM; ++fm) {
            const int off = ((wm * FM + fm) * 16 + l15) * 32 + sw;
            ah[fm] = *(const short8*)&sAh[off];
            al[fm] = *(const short8*)&sAl[off];
        }
#pragma unroll
        for (int fn = 0; fn < FN; ++fn) {
            const int off = ((wn * FN + fn) * 16 + l15) * 32 + sw;
            bh[fn] = *(const short8*)&sBh[off];
            bl[fn] = *(const short8*)&sBl[off];
        }
#pragma unroll
        for (int fm = 0; fm < FM; ++fm)
#pragma unroll
            for (int fn = 0; fn < FN; ++fn) {
                floatx4 a = acc[fm][fn];
                a = BMFMA(ah[fm], bh[fn], a);
                a = BMFMA(ah[fm], bl[fn], a);
                a = BMFMA(al[fm], bh[fn], a);
                acc[fm][fn] = a;
            }
    }

#pragma unroll
    for (int fm = 0; fm < FM; ++fm)
#pragma unroll
        for (int fn = 0; fn < FN; ++fn) {
            int col = n0 + (wn * FN + fn) * 16 + l15;
            float bv = bias[col];
#pragma unroll
            for (int r = 0; r < 4; ++r) {
                int row = m0 + (wm * FM + fm) * 16 + quad * 4 + r;
                C[(size_t)row * N + col] = acc[fm][fn][r] + bv;
            }
        }
}

// ---------------------------------------------------------------------------
// prep_qkv (unchanged, passing): RoPE + 1/8 q-scale + bf16 hi/lo split,
// Q/K: [bh][t][64], V: [bh][d][2048] transposed.
// ---------------------------------------------------------------------------
__global__ __launch_bounds__(256) void prep_qkv(
    const float* __restrict__ qkv,
    unsigned short* __restrict__ Qh, unsigned short* __restrict__ Ql,
    unsigned short* __restrict__ Kh, unsigned short* __restrict__ Kl,
    unsigned short* __restrict__ Vh, unsigned short* __restrict__ Vl)
{
    __shared__ float vt[64][65];
    const int tid = threadIdx.x;
    const int lin = blockIdx.x;
    const int tt = lin & 31, bh = lin >> 5;
    const int b = bh >> 4, h = bh & 15;
    const int r = tid >> 2;
    const int dblk = (tid & 3) * 16;
    const int tg = tt * 64 + r;
    const size_t src = (size_t)(b * SEQ + tg) * 3072 + h * 64 + dblk;
    const size_t dst = ((size_t)bh * SEQ + tg) * 64 + dblk;

    float q[16], k[16], v[16];
#pragma unroll
    for (int i = 0; i < 4; ++i) {
        *(float4*)&q[4 * i] = *(const float4*)(qkv + src + 4 * i);
        *(float4*)&k[4 * i] = *(const float4*)(qkv + src + 1024 + 4 * i);
        *(float4*)&v[4 * i] = *(const float4*)(qkv + src + 2048 + 4 * i);
    }
#pragma unroll
    for (int j = 0; j < 16; j += 2) {
        int pr = (dblk + j) >> 1;
        double e = (double)(2 * pr) / 64.0;
        float inv = (float)exp2(-e * 13.287712379549449);
        float ang = (float)tg * inv;
        float s, c;
        __sincosf(ang, &s, &c);
        float qe = q[j], qo = q[j + 1];
        q[j] = qe * c - qo * s; q[j + 1] = qe * s + qo * c;
        float ke = k[j], ko = k[j + 1];
        k[j] = ke * c - ko * s; k[j + 1] = ke * s + ko * c;
    }
    uint32_t ph[8], pl[8];
#pragma unroll
    for (int j = 0; j < 8; ++j) {
        float f0 = q[2 * j] * 0.125f, f1 = q[2 * j + 1] * 0.125f;
        unsigned short h0 = f2bf(f0), h1 = f2bf(f1);
        ph[j] = (uint32_t)h0 | ((uint32_t)h1 << 16);
        pl[j] = (uint32_t)f2bf(f0 - bf2f(h0)) | ((uint32_t)f2bf(f1 - bf2f(h1)) << 16);
    }
    *(uint4*)(Qh + dst) = *(uint4*)&ph[0]; *(uint4*)(Qh + dst + 8) = *(uint4*)&ph[4];
    *(uint4*)(Ql + dst) = *(uint4*)&pl[0]; *(uint4*)(Ql + dst + 8) = *(uint4*)&pl[4];
#pragma unroll
    for (int j = 0; j < 8; ++j) {
        float f0 = k[2 * j], f1 = k[2 * j + 1];
        unsigned short h0 = f2bf(f0), h1 = f2bf(f1);
        ph[j] = (uint32_t)h0 | ((uint32_t)h1 << 16);
        pl[j] = (uint32_t)f2bf(f0 - bf2f(h0)) | ((uint32_t)f2bf(f1 - bf2f(h1)) << 16);
    }
    *(uint4*)(Kh + dst) = *(uint4*)&ph[0]; *(uint4*)(Kh + dst + 8) = *(uint4*)&ph[4];
    *(uint4*)(Kl + dst) = *(uint4*)&pl[0]; *(uint4*)(Kl + dst + 8) = *(uint4*)&pl[4];

#pragma unroll
    for (int j = 0; j < 16; ++j) vt[r][dblk + j] = v[j];
    __syncthreads();
    const int d2 = tid >> 2;
    const int tb = (tid & 3) * 16;
#pragma unroll
    for (int j = 0; j < 8; ++j) {
        float f0 = vt[tb + 2 * j][d2], f1 = vt[tb + 2 * j + 1][d2];
        unsigned short h0 = f2bf(f0), h1 = f2bf(f1);
        ph[j] = (uint32_t)h0 | ((uint32_t)h1 << 16);
        pl[j] = (uint32_t)f2bf(f0 - bf2f(h0)) | ((uint32_t)f2bf(f1 - bf2f(h1)) << 16);
    }
    const size_t vdst = ((size_t)bh * 64 + d2) * SEQ + tt * 64 + tb;
    *(uint4*)(Vh + vdst) = *(uint4*)&ph[0]; *(uint4*)(Vh + vdst + 8) = *(uint4*)&ph[4];
    *(uint4*)(Vl + vdst) = *(uint4*)&pl[0]; *(uint4*)(Vl + vdst + 8) = *(uint4*)&pl[4];
}

// ---------------------------------------------------------------------------
// MFMA flash attention, R8: one block per (bh, qt) -> 1024 blocks, 4/CU
// (heavy-qt-first packing); K/V staging via global_load_lds DMA with the
// GEMM-proven xor-chunk mapping (0 conflicts, 0 staging VALU). Fixed-shift
// softmax + S^T + ones-MFMA l from R7 kept. LDS 40KB.
// ---------------------------------------------------------------------------
__global__ __launch_bounds__(256, 4) void flash_mfma(
    const unsigned short* __restrict__ Qh, const unsigned short* __restrict__ Ql,
    const unsigned short* __restrict__ Kh, const unsigned short* __restrict__ Kl,
    const unsigned short* __restrict__ Vh, const unsigned short* __restrict__ Vl,
    const int* __restrict__ am, unsigned short* __restrict__ attnx)
{
    // layout: [half][64 rows][32 shorts, xor-chunked] ; half = d-half (K) or
    // t-half (V); half stride 2048 shorts.
    __shared__ __align__(16) unsigned short sKh[4096];
    __shared__ __align__(16) unsigned short sKl[4096];
    __shared__ __align__(16) unsigned short sVh[4096];
    __shared__ __align__(16) unsigned short sVl[4096];
    __shared__ __align__(16) unsigned short sP[4096];    // 4 waves x [2][16][32]

    const int tid = threadIdx.x;
    const int lane = tid & 63, w = tid >> 6;
    const int l15 = lane & 15, quad = lane >> 4;
    const int lin = blockIdx.x;
    const int bh = lin & 31;
    const int qt = 31 - (lin >> 5);            // heavy q-tiles dispatched first
    const int b = bh >> 4, h = bh & 15;
    const int sw = (quad ^ ((l15 >> 1) & 3)) * 8;        // frag-read swizzle
    const int ch = (lane & 3) ^ ((lane >> 3) & 3);       // DMA staging chunk
    unsigned short* pbase = sP + w * 1024;

    short8 ones;
#pragma unroll
    for (int j = 0; j < 8; ++j) ones[j] = (short)0x3F80;  // bf16 1.0

    // Q fragments -> registers
    const size_t qb = ((size_t)bh * SEQ + qt * 64 + w * 16 + l15) * 64 + quad * 8;
    const short8 qh0 = *(const short8*)(Qh + qb);
    const short8 qh1 = *(const short8*)(Qh + qb + 32);
    const short8 ql0 = *(const short8*)(Ql + qb);
    const short8 ql1 = *(const short8*)(Ql + qb + 32);

    // per-lane DMA source bases (kt = 0)
    const size_t kRow0 = ((size_t)bh * SEQ + w * 16 + (lane >> 2)) * 64 + ch * 8;
    const size_t vRow  = ((size_t)bh * 64 + w * 16 + (lane >> 2)) * SEQ + ch * 8;

    floatx4 O[4];
    floatx4 lAcc = (floatx4)0.f;
#pragma unroll
    for (int nf = 0; nf < 4; ++nf) O[nf] = (floatx4)0.f;

    const int mg = qt * 64 + w * 16 + l15;               // this lane's q-row

    for (int kt = 0; kt <= qt; ++kt) {
        __syncthreads();   // all waves done reading previous K/V tiles
        {
            const size_t kg = kRow0 + (size_t)kt * 64 * 64;   // advance 64 t-rows
            const size_t vg = vRow + kt * 64;                  // advance 64 t-cols
            GLD_LDS16(Kh + kg,      sKh + w * 512);
            GLD_LDS16(Kh + kg + 32, sKh + 2048 + w * 512);
            GLD_LDS16(Kl + kg,      sKl + w * 512);
            GLD_LDS16(Kl + kg + 32, sKl + 2048 + w * 512);
            GLD_LDS16(Vh + vg,      sVh + w * 512);
            GLD_LDS16(Vh + vg + 32, sVh + 2048 + w * 512);
            GLD_LDS16(Vl + vg,      sVl + w * 512);
            GLD_LDS16(Vl + vg + 32, sVl + 2048 + w * 512);
        }
        __syncthreads();   // DMA (vmcnt) drained by barrier semantics

        const bool diag = (kt == qt);

        // ---- S^T = K Q^T (x3), exp, pack, stage P (wave-private) ----
#pragma unroll
        for (int nf = 0; nf < 4; ++nf) {
            const int base = (nf * 16 + l15) * 32 + sw;
            const short8 kh0 = *(const short8*)&sKh[base];
            const short8 kh1 = *(const short8*)&sKh[2048 + base];
            const short8 kl0 = *(const short8*)&sKl[base];
            const short8 kl1 = *(const short8*)&sKl[2048 + base];
            floatx4 s = (floatx4)0.f;
            s = BMFMA(kh0, qh0, s);
            s = BMFMA(kh1, qh1, s);
            s = BMFMA(kl0, qh0, s);
            s = BMFMA(kl1, qh1, s);
            s = BMFMA(kh0, ql0, s);
            s = BMFMA(kh1, ql1, s);

            const int tb = kt * 64 + nf * 16 + quad * 4;
            const int4 amv = *(const int4*)(am + b * SEQ + tb);
            float pv[4];
#pragma unroll
            for (int r = 0; r < 4; ++r) {
                bool ok = ((const int*)&amv)[r] != 0;
                if (diag) ok = ok && (tb + r <= mg);
                pv[r] = ok ? __expf(s[r] - 16.0f) : 0.0f;
            }
            ushort4 pk;
            pk.x = f2bf(pv[0]); pk.y = f2bf(pv[1]);
            pk.z = f2bf(pv[2]); pk.w = f2bf(pv[3]);
            const int pos = (((nf & 1) * 2 + (quad >> 1)) ^ ((l15 >> 1) & 3));
            *(ushort4*)(pbase + (nf >> 1) * 512 + l15 * 32 + pos * 8
                        + (quad & 1) * 4) = pk;
        }

        // ---- read P fragments (same-wave RAW: lgkmcnt only) ----
        const short8 pf0 = *(const short8*)(pbase + l15 * 32 + sw);
        const short8 pf1 = *(const short8*)(pbase + 512 + l15 * 32 + sw);

        // ---- l += P @ ones ; O += P @ (Vh + Vl) ----
        lAcc = BMFMA(pf0, ones, lAcc);
        lAcc = BMFMA(pf1, ones, lAcc);
#pragma unroll
        for (int nf = 0; nf < 4; ++nf) {
            const int vb = (nf * 16 + l15) * 32 + sw;
            floatx4 o = O[nf];
            o = BMFMA(pf0, *(const short8*)&sVh[vb], o);
            o = BMFMA(pf1, *(const short8*)&sVh[2048 + vb], o);
            o = BMFMA(pf0, *(const short8*)&sVl[vb], o);
            o = BMFMA(pf1, *(const short8*)&sVl[2048 + vb], o);
            O[nf] = o;
        }
    }

    // ---- finalize: divide by l, store bf16 hi|lo ----
    float rl[4];
#pragma unroll
    for (int r = 0; r < 4; ++r) rl[r] = 1.0f / lAcc[r];
#pragma unroll
    for (int nf = 0; nf < 4; ++nf)
#pragma unroll
        for (int r = 0; r < 4; ++r) {
            const int tok = b * SEQ + qt * 64 + w * 16 + quad * 4 + r;
            const int col = h * 64 + nf * 16 + l15;
            const float val = O[nf][r] * rl[r];
            const unsigned short hi = f2bf(val);
            const unsigned short lo = f2bf(val - bf2f(hi));
            attnx[(size_t)tok * 2048 + col] = hi;
            attnx[(size_t)tok * 2048 + 1024 + col] = lo;
        }
}

// ---------------------------------------------------------------------------
extern "C" void kernel_launch(void* const* d_in, const int* in_sizes, int n_in,
                              void* d_out, int out_size, void* d_ws, size_t ws_size,
                              hipStream_t stream)
{
    const float* x    = (const float*)d_in[0];
    const int*   am   = (const int*)d_in[1];
    const float* Wqkv = (const float*)d_in[2];
    const float* bqkv = (const float*)d_in[3];
    const float* Wout = (const float*)d_in[4];
    const float* bout = (const float*)d_in[5];
    float* out = (float*)d_out;

    // ws layout (113.2 MB, unchanged):
    //   Bt 12.58MB | qkv fp32 50.33MB (reused as attnx bf16 after prep) |
    //   Qh Ql Kh Kl Vh Vl 8.39MB each (Vh+Vl doubles as Ax before prep)
    char* ws = (char*)d_ws;
    unsigned short* Bt = (unsigned short*)ws;
    float* qkv = (float*)(ws + 12582912);
    unsigned short* attnx = (unsigned short*)qkv;        // alias: qkv dead after prep
    unsigned short* Qh = (unsigned short*)(ws + 62914560);
    unsigned short* Ql = Qh + 4194304;
    unsigned short* Kh = Ql + 4194304;
    unsigned short* Kl = Kh + 4194304;
    unsigned short* Vh = Kl + 4194304;
    unsigned short* Vl = Vh + 4194304;
    unsigned short* Ax = Vh;                             // alias: dead after gemm1

    // 0) split x -> bf16 hi|lo
    split_a<<<4096, 256, 0, stream>>>(x, Ax);

    // 1) qkv = x @ W_qkv + b   (fused-x3 bf16 MFMA, swizzled LDS, DMA staging)
    split_w_t<<<dim3(96, 32), 256, 0, stream>>>(Wqkv, 3072, Bt);
    gemm_mfma_x3f<2, 2, 4, 4><<<dim3(24, 32), 256, 0, stream>>>(
        Ax, Bt, bqkv, qkv, TOKENS, 3072);

    // 2) RoPE + scale + split + V transpose (overwrites Ax region - ordered)
    prep_qkv<<<1024, 256, 0, stream>>>(qkv, Qh, Ql, Kh, Kl, Vh, Vl);

    // 3) MFMA flash attention -> attnx (1024 blocks, heavy-first, DMA staging)
    flash_mfma<<<1024, 256, 0, stream>>>(Qh, Ql, Kh, Kl, Vh, Vl, am, attnx);

    // 4) out = attn @ W_out + b
    split_w_t<<<dim3(32, 32), 256, 0, stream>>>(Wout, 1024, Bt);
    gemm_mfma_x3f<2, 2, 2, 4><<<dim3(8, 64), 256, 0, stream>>>(
        attnx, Bt, bout, out, TOKENS, 1024);
}

// Round 9
// 286.265 us; speedup vs baseline: 1.1931x; 1.1257x over previous
//
#include <hip/hip_runtime.h>
#include <math.h>
#include <stdint.h>

#define D_MODEL 1024
#define N_HEADS 16
#define HEAD_DIM 64
#define BATCH 2
#define SEQ 2048
#define TOKENS (BATCH * SEQ)   // 4096

typedef __attribute__((ext_vector_type(8))) short short8;   // 8 bf16 = 4 VGPRs
typedef __attribute__((ext_vector_type(4))) float floatx4;  // MFMA C/D frag

#define BMFMA(a, b, c) __builtin_amdgcn_mfma_f32_16x16x32_bf16(a, b, c, 0, 0, 0)

__device__ __forceinline__ unsigned short f2bf(float f) {
    uint32_t u = __float_as_uint(f);
    u += 0x7fffu + ((u >> 16) & 1u);
    return (unsigned short)(u >> 16);
}
__device__ __forceinline__ float bf2f(unsigned short h) {
    return __uint_as_float(((uint32_t)h) << 16);
}

// async global -> LDS, 16B per lane; LDS dest = wave-uniform base + lane*16
#define GLD_LDS16(gp, lp) __builtin_amdgcn_global_load_lds(                 \
    (const __attribute__((address_space(1))) void*)(gp),                    \
    (__attribute__((address_space(3))) void*)(lp), 16, 0, 0)

// ---------------------------------------------------------------------------
// Merged input prep: blocks [0,4096) = split_a (x -> Ax hi|lo),
// blocks [4096, 7168) = split/transpose W_qkv -> Bt.
// ---------------------------------------------------------------------------
__global__ __launch_bounds__(256) void split_inputs(
    const float* __restrict__ X, const float* __restrict__ Wqkv,
    unsigned short* __restrict__ Ax, unsigned short* __restrict__ Bt)
{
    __shared__ float t[32][33];
    const int tid = threadIdx.x;
    const int bid = blockIdx.x;
    if (bid < 4096) {
        const int idx = bid * 256 + tid;
        const int row = idx >> 8;
        const int c = (idx & 255) * 4;
        float4 v = *(const float4*)(X + (size_t)row * 1024 + c);
        float f[4] = {v.x, v.y, v.z, v.w};
        uint32_t hp[2], lp[2];
#pragma unroll
        for (int j = 0; j < 2; ++j) {
            unsigned short h0 = f2bf(f[2 * j]), h1 = f2bf(f[2 * j + 1]);
            hp[j] = (uint32_t)h0 | ((uint32_t)h1 << 16);
            lp[j] = (uint32_t)f2bf(f[2 * j] - bf2f(h0)) |
                    ((uint32_t)f2bf(f[2 * j + 1] - bf2f(h1)) << 16);
        }
        *(uint2*)(Ax + (size_t)row * 2048 + c) = make_uint2(hp[0], hp[1]);
        *(uint2*)(Ax + (size_t)row * 2048 + 1024 + c) = make_uint2(lp[0], lp[1]);
    } else {
        const int id = bid - 4096;                 // 0..3071
        const int n0 = (id % 96) * 32, k0 = (id / 96) * 32;
        const int c = tid & 31, r = tid >> 5;
#pragma unroll
        for (int i = 0; i < 4; ++i)
            t[r + 8 * i][c] = Wqkv[(size_t)(k0 + r + 8 * i) * 3072 + n0 + c];
        __syncthreads();
#pragma unroll
        for (int i = 0; i < 4; ++i) {
            int dn = r + 8 * i;
            float f = t[c][dn];
            unsigned short hi = f2bf(f);
            unsigned short lo = f2bf(f - bf2f(hi));
            size_t row = (size_t)(n0 + dn) * 2048;
            Bt[row + k0 + c] = hi;
            Bt[row + 1024 + k0 + c] = lo;
        }
    }
}

// ---------------------------------------------------------------------------
// Weight transpose + bf16 hi/lo split (standalone, for W_out before gemm2)
// ---------------------------------------------------------------------------
__global__ __launch_bounds__(256) void split_w_t(
    const float* __restrict__ W, int N, unsigned short* __restrict__ Bt)
{
    __shared__ float t[32][33];
    const int tid = threadIdx.x;
    const int n0 = blockIdx.x * 32, k0 = blockIdx.y * 32;
    const int c = tid & 31, r = tid >> 5;
#pragma unroll
    for (int i = 0; i < 4; ++i)
        t[r + 8 * i][c] = W[(size_t)(k0 + r + 8 * i) * N + n0 + c];
    __syncthreads();
#pragma unroll
    for (int i = 0; i < 4; ++i) {
        int dn = r + 8 * i;
        float f = t[c][dn];
        unsigned short hi = f2bf(f);
        unsigned short lo = f2bf(f - bf2f(hi));
        size_t row = (size_t)(n0 + dn) * 2048;
        Bt[row + k0 + c] = hi;
        Bt[row + 1024 + k0 + c] = lo;
    }
}

// ---------------------------------------------------------------------------
// FUSED x3 bf16 MFMA GEMM (R6 structure) + 1D grid with 8-wide M-supertile
// swizzle for L2 locality. nTiles = N/BN; M/BM must be a multiple of 8.
// ---------------------------------------------------------------------------
template<int WM, int WN, int FM, int FN>
__global__ __launch_bounds__(256) void gemm_mfma_x3f(
    const unsigned short* __restrict__ Ax, const unsigned short* __restrict__ Bt,
    const float* __restrict__ bias, float* __restrict__ C, int M, int N,
    int nTiles)
{
    constexpr int BM = WM * FM * 16;
    constexpr int BN = WN * FN * 16;
    constexpr int NA = BM / 64;
    constexpr int NB = BN / 64;

    __shared__ __align__(16) unsigned short sAh[BM * 32];
    __shared__ __align__(16) unsigned short sAl[BM * 32];
    __shared__ __align__(16) unsigned short sBh[BN * 32];
    __shared__ __align__(16) unsigned short sBl[BN * 32];

    const int tid = threadIdx.x;
    const int w = tid >> 6, lane = tid & 63;
    const int l15 = lane & 15, quad = lane >> 4;
    const int wm = w / WN, wn = w % WN;

    // L2 swizzle: groups of 8*nTiles blocks cover 8 M-tiles x all N-tiles
    const int lin = blockIdx.x;
    const int msuper = lin / (8 * nTiles);
    const int rem = lin % (8 * nTiles);
    const int m0 = (msuper * 8 + (rem & 7)) * BM;
    const int n0 = (rem >> 3) * BN;

    const int ch = (lane & 3) ^ ((lane >> 3) & 3);       // staging swizzle
    const int sw = (quad ^ ((l15 >> 1) & 3)) * 8;        // frag-read swizzle

    const unsigned short* aG[NA];
    const unsigned short* bG[NB];
#pragma unroll
    for (int i = 0; i < NA; ++i)
        aG[i] = Ax + (size_t)(m0 + (w * NA + i) * 16 + (lane >> 2)) * 2048
                   + ch * 8;
#pragma unroll
    for (int i = 0; i < NB; ++i)
        bG[i] = Bt + (size_t)(n0 + (w * NB + i) * 16 + (lane >> 2)) * 2048
                   + ch * 8;

    floatx4 acc[FM][FN];
#pragma unroll
    for (int fm = 0; fm < FM; ++fm)
#pragma unroll
        for (int fn = 0; fn < FN; ++fn) acc[fm][fn] = (floatx4)0.f;

    for (int ks = 0; ks < 32; ++ks) {
        const int ko = ks * 32;          // hi at ko, lo at 1024+ko
        __syncthreads();
#pragma unroll
        for (int i = 0; i < NA; ++i) {
            GLD_LDS16(aG[i] + ko,        sAh + (w * NA + i) * 512);
            GLD_LDS16(aG[i] + 1024 + ko, sAl + (w * NA + i) * 512);
        }
#pragma unroll
        for (int i = 0; i < NB; ++i) {
            GLD_LDS16(bG[i] + ko,        sBh + (w * NB + i) * 512);
            GLD_LDS16(bG[i] + 1024 + ko, sBl + (w * NB + i) * 512);
        }
        __syncthreads();

        short8 ah[FM], al[FM], bh[FN], bl[FN];
#pragma unroll
        for (int fm = 0; fm < FM; ++fm) {
            const int off = ((wm * FM + fm) * 16 + l15) * 32 + sw;
            ah[fm] = *(const short8*)&sAh[off];
            al[fm] = *(const short8*)&sAl[off];
        }
#pragma unroll
        for (int fn = 0; fn < FN; ++fn) {
            const int off = ((wn * FN + fn) * 16 + l15) * 32 + sw;
            bh[fn] = *(const short8*)&sBh[off];
            bl[fn] = *(const short8*)&sBl[off];
        }
#pragma unroll
        for (int fm = 0; fm < FM; ++fm)
#pragma unroll
            for (int fn = 0; fn < FN; ++fn) {
                floatx4 a = acc[fm][fn];
                a = BMFMA(ah[fm], bh[fn], a);
                a = BMFMA(ah[fm], bl[fn], a);
                a = BMFMA(al[fm], bh[fn], a);
                acc[fm][fn] = a;
            }
    }

#pragma unroll
    for (int fm = 0; fm < FM; ++fm)
#pragma unroll
        for (int fn = 0; fn < FN; ++fn) {
            int col = n0 + (wn * FN + fn) * 16 + l15;
            float bv = bias[col];
#pragma unroll
            for (int r = 0; r < 4; ++r) {
                int row = m0 + (wm * FM + fm) * 16 + quad * 4 + r;
                C[(size_t)row * N + col] = acc[fm][fn][r] + bv;
            }
        }
}

// ---------------------------------------------------------------------------
// Single-precision bf16 MFMA GEMM (for out-projection). BK=64 (two 32-chunks
// per barrier), same swizzle, runtime A/B row strides. nTiles = N/BN.
// ---------------------------------------------------------------------------
template<int WM, int WN, int FM, int FN>
__global__ __launch_bounds__(256) void gemm_mfma_s(
    const unsigned short* __restrict__ A, int lda,
    const unsigned short* __restrict__ Bt, int ldb,
    const float* __restrict__ bias, float* __restrict__ C, int M, int N,
    int nTiles)
{
    constexpr int BM = WM * FM * 16;
    constexpr int BN = WN * FN * 16;
    constexpr int NA = BM / 64;
    constexpr int NB = BN / 64;

    __shared__ __align__(16) unsigned short sA0[BM * 32];
    __shared__ __align__(16) unsigned short sA1[BM * 32];
    __shared__ __align__(16) unsigned short sB0[BN * 32];
    __shared__ __align__(16) unsigned short sB1[BN * 32];

    const int tid = threadIdx.x;
    const int w = tid >> 6, lane = tid & 63;
    const int l15 = lane & 15, quad = lane >> 4;
    const int wm = w / WN, wn = w % WN;

    const int lin = blockIdx.x;
    const int msuper = lin / (8 * nTiles);
    const int rem = lin % (8 * nTiles);
    const int m0 = (msuper * 8 + (rem & 7)) * BM;
    const int n0 = (rem >> 3) * BN;

    const int ch = (lane & 3) ^ ((lane >> 3) & 3);
    const int sw = (quad ^ ((l15 >> 1) & 3)) * 8;

    const unsigned short* aG[NA];
    const unsigned short* bG[NB];
#pragma unroll
    for (int i = 0; i < NA; ++i)
        aG[i] = A + (size_t)(m0 + (w * NA + i) * 16 + (lane >> 2)) * lda + ch * 8;
#pragma unroll
    for (int i = 0; i < NB; ++i)
        bG[i] = Bt + (size_t)(n0 + (w * NB + i) * 16 + (lane >> 2)) * ldb + ch * 8;

    floatx4 acc[FM][FN];
#pragma unroll
    for (int fm = 0; fm < FM; ++fm)
#pragma unroll
        for (int fn = 0; fn < FN; ++fn) acc[fm][fn] = (floatx4)0.f;

    for (int ks = 0; ks < 16; ++ks) {
        const int ko = ks * 64;
        __syncthreads();
#pragma unroll
        for (int i = 0; i < NA; ++i) {
            GLD_LDS16(aG[i] + ko,      sA0 + (w * NA + i) * 512);
            GLD_LDS16(aG[i] + ko + 32, sA1 + (w * NA + i) * 512);
        }
#pragma unroll
        for (int i = 0; i < NB; ++i) {
            GLD_LDS16(bG[i] + ko,      sB0 + (w * NB + i) * 512);
            GLD_LDS16(bG[i] + ko + 32, sB1 + (w * NB + i) * 512);
        }
        __syncthreads();

        short8 a0[FM], a1[FM], b0[FN], b1[FN];
#pragma unroll
        for (int fm = 0; fm < FM; ++fm) {
            const int off = ((wm * FM + fm) * 16 + l15) * 32 + sw;
            a0[fm] = *(const short8*)&sA0[off];
            a1[fm] = *(const short8*)&sA1[off];
        }
#pragma unroll
        for (int fn = 0; fn < FN; ++fn) {
            const int off = ((wn * FN + fn) * 16 + l15) * 32 + sw;
            b0[fn] = *(const short8*)&sB0[off];
            b1[fn] = *(const short8*)&sB1[off];
        }
#pragma unroll
        for (int fm = 0; fm < FM; ++fm)
#pragma unroll
            for (int fn = 0; fn < FN; ++fn) {
                floatx4 a = acc[fm][fn];
                a = BMFMA(a0[fm], b0[fn], a);
                a = BMFMA(a1[fm], b1[fn], a);
                acc[fm][fn] = a;
            }
    }

#pragma unroll
    for (int fm = 0; fm < FM; ++fm)
#pragma unroll
        for (int fn = 0; fn < FN; ++fn) {
            int col = n0 + (wn * FN + fn) * 16 + l15;
            float bv = bias[col];
#pragma unroll
            for (int r = 0; r < 4; ++r) {
                int row = m0 + (wm * FM + fm) * 16 + quad * 4 + r;
                C[(size_t)row * N + col] = acc[fm][fn][r] + bv;
            }
        }
}

// ---------------------------------------------------------------------------
// prep_qkv: RoPE + 1/8 q-scale + bf16 hi/lo split. Vl dropped (R9):
// Q/K hi+lo [bh][t][64]; V hi only [bh][d][2048] transposed.
// ---------------------------------------------------------------------------
__global__ __launch_bounds__(256) void prep_qkv(
    const float* __restrict__ qkv,
    unsigned short* __restrict__ Qh, unsigned short* __restrict__ Ql,
    unsigned short* __restrict__ Kh, unsigned short* __restrict__ Kl,
    unsigned short* __restrict__ Vh)
{
    __shared__ float vt[64][65];
    const int tid = threadIdx.x;
    const int lin = blockIdx.x;
    const int tt = lin & 31, bh = lin >> 5;
    const int b = bh >> 4, h = bh & 15;
    const int r = tid >> 2;
    const int dblk = (tid & 3) * 16;
    const int tg = tt * 64 + r;
    const size_t src = (size_t)(b * SEQ + tg) * 3072 + h * 64 + dblk;
    const size_t dst = ((size_t)bh * SEQ + tg) * 64 + dblk;

    float q[16], k[16], v[16];
#pragma unroll
    for (int i = 0; i < 4; ++i) {
        *(float4*)&q[4 * i] = *(const float4*)(qkv + src + 4 * i);
        *(float4*)&k[4 * i] = *(const float4*)(qkv + src + 1024 + 4 * i);
        *(float4*)&v[4 * i] = *(const float4*)(qkv + src + 2048 + 4 * i);
    }
#pragma unroll
    for (int j = 0; j < 16; j += 2) {
        int pr = (dblk + j) >> 1;
        double e = (double)(2 * pr) / 64.0;
        float inv = (float)exp2(-e * 13.287712379549449);
        float ang = (float)tg * inv;
        float s, c;
        __sincosf(ang, &s, &c);
        float qe = q[j], qo = q[j + 1];
        q[j] = qe * c - qo * s; q[j + 1] = qe * s + qo * c;
        float ke = k[j], ko = k[j + 1];
        k[j] = ke * c - ko * s; k[j + 1] = ke * s + ko * c;
    }
    uint32_t ph[8], pl[8];
#pragma unroll
    for (int j = 0; j < 8; ++j) {
        float f0 = q[2 * j] * 0.125f, f1 = q[2 * j + 1] * 0.125f;
        unsigned short h0 = f2bf(f0), h1 = f2bf(f1);
        ph[j] = (uint32_t)h0 | ((uint32_t)h1 << 16);
        pl[j] = (uint32_t)f2bf(f0 - bf2f(h0)) | ((uint32_t)f2bf(f1 - bf2f(h1)) << 16);
    }
    *(uint4*)(Qh + dst) = *(uint4*)&ph[0]; *(uint4*)(Qh + dst + 8) = *(uint4*)&ph[4];
    *(uint4*)(Ql + dst) = *(uint4*)&pl[0]; *(uint4*)(Ql + dst + 8) = *(uint4*)&pl[4];
#pragma unroll
    for (int j = 0; j < 8; ++j) {
        float f0 = k[2 * j], f1 = k[2 * j + 1];
        unsigned short h0 = f2bf(f0), h1 = f2bf(f1);
        ph[j] = (uint32_t)h0 | ((uint32_t)h1 << 16);
        pl[j] = (uint32_t)f2bf(f0 - bf2f(h0)) | ((uint32_t)f2bf(f1 - bf2f(h1)) << 16);
    }
    *(uint4*)(Kh + dst) = *(uint4*)&ph[0]; *(uint4*)(Kh + dst + 8) = *(uint4*)&ph[4];
    *(uint4*)(Kl + dst) = *(uint4*)&pl[0]; *(uint4*)(Kl + dst + 8) = *(uint4*)&pl[4];

#pragma unroll
    for (int j = 0; j < 16; ++j) vt[r][dblk + j] = v[j];
    __syncthreads();
    const int d2 = tid >> 2;
    const int tb = (tid & 3) * 16;
#pragma unroll
    for (int j = 0; j < 8; ++j) {
        float f0 = vt[tb + 2 * j][d2], f1 = vt[tb + 2 * j + 1][d2];
        ph[j] = (uint32_t)f2bf(f0) | ((uint32_t)f2bf(f1) << 16);
    }
    const size_t vdst = ((size_t)bh * 64 + d2) * SEQ + tt * 64 + tb;
    *(uint4*)(Vh + vdst) = *(uint4*)&ph[0]; *(uint4*)(Vh + vdst + 8) = *(uint4*)&ph[4];
}

// ---------------------------------------------------------------------------
// MFMA flash attention, R9: Vl dropped (P already bf16 — V-lo is below the
// noise floor). 34 MFMA/iter, 6 DMA loads/iter, LDS 32KB. attnx written as
// plain bf16 [tok][1024]. Otherwise R8 structure (1024 blocks, heavy-first).
// ---------------------------------------------------------------------------
__global__ __launch_bounds__(256, 4) void flash_mfma(
    const unsigned short* __restrict__ Qh, const unsigned short* __restrict__ Ql,
    const unsigned short* __restrict__ Kh, const unsigned short* __restrict__ Kl,
    const unsigned short* __restrict__ Vh,
    const int* __restrict__ am, unsigned short* __restrict__ attnx)
{
    __shared__ __align__(16) unsigned short sKh[4096];
    __shared__ __align__(16) unsigned short sKl[4096];
    __shared__ __align__(16) unsigned short sVh[4096];
    __shared__ __align__(16) unsigned short sP[4096];

    const int tid = threadIdx.x;
    const int lane = tid & 63, w = tid >> 6;
    const int l15 = lane & 15, quad = lane >> 4;
    const int lin = blockIdx.x;
    const int bh = lin & 31;
    const int qt = 31 - (lin >> 5);            // heavy q-tiles dispatched first
    const int b = bh >> 4, h = bh & 15;
    const int sw = (quad ^ ((l15 >> 1) & 3)) * 8;
    const int ch = (lane & 3) ^ ((lane >> 3) & 3);
    unsigned short* pbase = sP + w * 1024;

    short8 ones;
#pragma unroll
    for (int j = 0; j < 8; ++j) ones[j] = (short)0x3F80;  // bf16 1.0

    const size_t qb = ((size_t)bh * SEQ + qt * 64 + w * 16 + l15) * 64 + quad * 8;
    const short8 qh0 = *(const short8*)(Qh + qb);
    const short8 qh1 = *(const short8*)(Qh + qb + 32);
    const short8 ql0 = *(const short8*)(Ql + qb);
    const short8 ql1 = *(const short8*)(Ql + qb + 32);

    const size_t kRow0 = ((size_t)bh * SEQ + w * 16 + (lane >> 2)) * 64 + ch * 8;
    const size_t vRow  = ((size_t)bh * 64 + w * 16 + (lane >> 2)) * SEQ + ch * 8;

    floatx4 O[4];
    floatx4 lAcc = (floatx4)0.f;
#pragma unroll
    for (int nf = 0; nf < 4; ++nf) O[nf] = (floatx4)0.f;

    const int mg = qt * 64 + w * 16 + l15;

    for (int kt = 0; kt <= qt; ++kt) {
        __syncthreads();
        {
            const size_t kg = kRow0 + (size_t)kt * 64 * 64;
            const size_t vg = vRow + kt * 64;
            GLD_LDS16(Kh + kg,      sKh + w * 512);
            GLD_LDS16(Kh + kg + 32, sKh + 2048 + w * 512);
            GLD_LDS16(Kl + kg,      sKl + w * 512);
            GLD_LDS16(Kl + kg + 32, sKl + 2048 + w * 512);
            GLD_LDS16(Vh + vg,      sVh + w * 512);
            GLD_LDS16(Vh + vg + 32, sVh + 2048 + w * 512);
        }
        __syncthreads();

        const bool diag = (kt == qt);

        // ---- S^T = K Q^T (x3), exp, pack, stage P (wave-private) ----
#pragma unroll
        for (int nf = 0; nf < 4; ++nf) {
            const int base = (nf * 16 + l15) * 32 + sw;
            const short8 kh0 = *(const short8*)&sKh[base];
            const short8 kh1 = *(const short8*)&sKh[2048 + base];
            const short8 kl0 = *(const short8*)&sKl[base];
            const short8 kl1 = *(const short8*)&sKl[2048 + base];
            floatx4 s = (floatx4)0.f;
            s = BMFMA(kh0, qh0, s);
            s = BMFMA(kh1, qh1, s);
            s = BMFMA(kl0, qh0, s);
            s = BMFMA(kl1, qh1, s);
            s = BMFMA(kh0, ql0, s);
            s = BMFMA(kh1, ql1, s);

            const int tb = kt * 64 + nf * 16 + quad * 4;
            const int4 amv = *(const int4*)(am + b * SEQ + tb);
            float pv[4];
#pragma unroll
            for (int r = 0; r < 4; ++r) {
                bool ok = ((const int*)&amv)[r] != 0;
                if (diag) ok = ok && (tb + r <= mg);
                pv[r] = ok ? __expf(s[r] - 16.0f) : 0.0f;
            }
            ushort4 pk;
            pk.x = f2bf(pv[0]); pk.y = f2bf(pv[1]);
            pk.z = f2bf(pv[2]); pk.w = f2bf(pv[3]);
            const int pos = (((nf & 1) * 2 + (quad >> 1)) ^ ((l15 >> 1) & 3));
            *(ushort4*)(pbase + (nf >> 1) * 512 + l15 * 32 + pos * 8
                        + (quad & 1) * 4) = pk;
        }

        const short8 pf0 = *(const short8*)(pbase + l15 * 32 + sw);
        const short8 pf1 = *(const short8*)(pbase + 512 + l15 * 32 + sw);

        // ---- l += P @ ones ; O += P @ Vh ----
        lAcc = BMFMA(pf0, ones, lAcc);
        lAcc = BMFMA(pf1, ones, lAcc);
#pragma unroll
        for (int nf = 0; nf < 4; ++nf) {
            const int vb = (nf * 16 + l15) * 32 + sw;
            floatx4 o = O[nf];
            o = BMFMA(pf0, *(const short8*)&sVh[vb], o);
            o = BMFMA(pf1, *(const short8*)&sVh[2048 + vb], o);
            O[nf] = o;
        }
    }

    // ---- finalize: divide by l, store plain bf16 ----
    float rl[4];
#pragma unroll
    for (int r = 0; r < 4; ++r) rl[r] = 1.0f / lAcc[r];
#pragma unroll
    for (int nf = 0; nf < 4; ++nf)
#pragma unroll
        for (int r = 0; r < 4; ++r) {
            const int tok = b * SEQ + qt * 64 + w * 16 + quad * 4 + r;
            const int col = h * 64 + nf * 16 + l15;
            attnx[(size_t)tok * 1024 + col] = f2bf(O[nf][r] * rl[r]);
        }
}

// ---------------------------------------------------------------------------
extern "C" void kernel_launch(void* const* d_in, const int* in_sizes, int n_in,
                              void* d_out, int out_size, void* d_ws, size_t ws_size,
                              hipStream_t stream)
{
    const float* x    = (const float*)d_in[0];
    const int*   am   = (const int*)d_in[1];
    const float* Wqkv = (const float*)d_in[2];
    const float* bqkv = (const float*)d_in[3];
    const float* Wout = (const float*)d_in[4];
    const float* bout = (const float*)d_in[5];
    float* out = (float*)d_out;

    // ws layout (113.2 MB, unchanged footprint):
    //   Bt 12.58MB | qkv fp32 50.33MB (start reused as attnx bf16 after prep) |
    //   Qh Ql Kh Kl Vh (Vl slot unused) ; Ax aliases Vh+VlSlot before prep
    char* ws = (char*)d_ws;
    unsigned short* Bt = (unsigned short*)ws;
    float* qkv = (float*)(ws + 12582912);
    unsigned short* attnx = (unsigned short*)qkv;        // alias: qkv dead after prep
    unsigned short* Qh = (unsigned short*)(ws + 62914560);
    unsigned short* Ql = Qh + 4194304;
    unsigned short* Kh = Ql + 4194304;
    unsigned short* Kl = Kh + 4194304;
    unsigned short* Vh = Kl + 4194304;
    unsigned short* Ax = Vh;                             // alias: dead after gemm1

    // 0) split x -> Ax (hi|lo) and W_qkv -> Bt, one launch
    split_inputs<<<7168, 256, 0, stream>>>(x, Wqkv, Ax, Bt);

    // 1) qkv = x @ W_qkv + b  (fused-x3, L2-swizzled 1D grid)
    gemm_mfma_x3f<2, 2, 4, 4><<<768, 256, 0, stream>>>(
        Ax, Bt, bqkv, qkv, TOKENS, 3072, 24);

    // 2) RoPE + scale + split (no Vl)
    prep_qkv<<<1024, 256, 0, stream>>>(qkv, Qh, Ql, Kh, Kl, Vh);

    // 3) MFMA flash attention -> attnx (plain bf16)
    flash_mfma<<<1024, 256, 0, stream>>>(Qh, Ql, Kh, Kl, Vh, am, attnx);

    // 4) out = attn @ W_out + b  (single-bf16 GEMM; uses hi half of Bt)
    split_w_t<<<dim3(32, 32), 256, 0, stream>>>(Wout, 1024, Bt);
    gemm_mfma_s<2, 2, 2, 4><<<512, 256, 0, stream>>>(
        attnx, 1024, Bt, 2048, bout, out, TOKENS, 1024, 8);
}

// Round 10
// 254.536 us; speedup vs baseline: 1.3419x; 1.1247x over previous
//
#include <hip/hip_runtime.h>
#include <math.h>
#include <stdint.h>

#define D_MODEL 1024
#define N_HEADS 16
#define HEAD_DIM 64
#define BATCH 2
#define SEQ 2048
#define TOKENS (BATCH * SEQ)   // 4096

typedef __attribute__((ext_vector_type(8))) short short8;   // 8 bf16 = 4 VGPRs
typedef __attribute__((ext_vector_type(4))) float floatx4;  // MFMA C/D frag

#define BMFMA(a, b, c) __builtin_amdgcn_mfma_f32_16x16x32_bf16(a, b, c, 0, 0, 0)

__device__ __forceinline__ unsigned short f2bf(float f) {
    uint32_t u = __float_as_uint(f);
    u += 0x7fffu + ((u >> 16) & 1u);
    return (unsigned short)(u >> 16);
}
__device__ __forceinline__ float bf2f(unsigned short h) {
    return __uint_as_float(((uint32_t)h) << 16);
}

// async global -> LDS, 16B per lane; LDS dest = wave-uniform base + lane*16
#define GLD_LDS16(gp, lp) __builtin_amdgcn_global_load_lds(                 \
    (const __attribute__((address_space(1))) void*)(gp),                    \
    (__attribute__((address_space(3))) void*)(lp), 16, 0, 0)

// ---------------------------------------------------------------------------
// Merged input prep: blocks [0,4096) = split_a (x -> Ax hi|lo),
// blocks [4096, 7168) = split/transpose W_qkv -> Bt.
// ---------------------------------------------------------------------------
__global__ __launch_bounds__(256) void split_inputs(
    const float* __restrict__ X, const float* __restrict__ Wqkv,
    unsigned short* __restrict__ Ax, unsigned short* __restrict__ Bt)
{
    __shared__ float t[32][33];
    const int tid = threadIdx.x;
    const int bid = blockIdx.x;
    if (bid < 4096) {
        const int idx = bid * 256 + tid;
        const int row = idx >> 8;
        const int c = (idx & 255) * 4;
        float4 v = *(const float4*)(X + (size_t)row * 1024 + c);
        float f[4] = {v.x, v.y, v.z, v.w};
        uint32_t hp[2], lp[2];
#pragma unroll
        for (int j = 0; j < 2; ++j) {
            unsigned short h0 = f2bf(f[2 * j]), h1 = f2bf(f[2 * j + 1]);
            hp[j] = (uint32_t)h0 | ((uint32_t)h1 << 16);
            lp[j] = (uint32_t)f2bf(f[2 * j] - bf2f(h0)) |
                    ((uint32_t)f2bf(f[2 * j + 1] - bf2f(h1)) << 16);
        }
        *(uint2*)(Ax + (size_t)row * 2048 + c) = make_uint2(hp[0], hp[1]);
        *(uint2*)(Ax + (size_t)row * 2048 + 1024 + c) = make_uint2(lp[0], lp[1]);
    } else {
        const int id = bid - 4096;                 // 0..3071
        const int n0 = (id % 96) * 32, k0 = (id / 96) * 32;
        const int c = tid & 31, r = tid >> 5;
#pragma unroll
        for (int i = 0; i < 4; ++i)
            t[r + 8 * i][c] = Wqkv[(size_t)(k0 + r + 8 * i) * 3072 + n0 + c];
        __syncthreads();
#pragma unroll
        for (int i = 0; i < 4; ++i) {
            int dn = r + 8 * i;
            float f = t[c][dn];
            unsigned short hi = f2bf(f);
            unsigned short lo = f2bf(f - bf2f(hi));
            size_t row = (size_t)(n0 + dn) * 2048;
            Bt[row + k0 + c] = hi;
            Bt[row + 1024 + k0 + c] = lo;
        }
    }
}

// ---------------------------------------------------------------------------
// Weight transpose + bf16 hi/lo split (standalone, for W_out before gemm2)
// ---------------------------------------------------------------------------
__global__ __launch_bounds__(256) void split_w_t(
    const float* __restrict__ W, int N, unsigned short* __restrict__ Bt)
{
    __shared__ float t[32][33];
    const int tid = threadIdx.x;
    const int n0 = blockIdx.x * 32, k0 = blockIdx.y * 32;
    const int c = tid & 31, r = tid >> 5;
#pragma unroll
    for (int i = 0; i < 4; ++i)
        t[r + 8 * i][c] = W[(size_t)(k0 + r + 8 * i) * N + n0 + c];
    __syncthreads();
#pragma unroll
    for (int i = 0; i < 4; ++i) {
        int dn = r + 8 * i;
        float f = t[c][dn];
        unsigned short hi = f2bf(f);
        unsigned short lo = f2bf(f - bf2f(hi));
        size_t row = (size_t)(n0 + dn) * 2048;
        Bt[row + k0 + c] = hi;
        Bt[row + 1024 + k0 + c] = lo;
    }
}

// ---------------------------------------------------------------------------
// FUSED x3 bf16 MFMA GEMM (R6 structure), 1D grid + 8-wide M-supertile
// swizzle. A: Ax [M][2048] hi|lo. B: Bt rows [n][2048] hi|lo. C stride ldc.
// ---------------------------------------------------------------------------
template<int WM, int WN, int FM, int FN>
__global__ __launch_bounds__(256) void gemm_mfma_x3f(
    const unsigned short* __restrict__ Ax, const unsigned short* __restrict__ Bt,
    const float* __restrict__ bias, float* __restrict__ C, int ldc, int nTiles)
{
    constexpr int BM = WM * FM * 16;
    constexpr int BN = WN * FN * 16;
    constexpr int NA = BM / 64;
    constexpr int NB = BN / 64;

    __shared__ __align__(16) unsigned short sAh[BM * 32];
    __shared__ __align__(16) unsigned short sAl[BM * 32];
    __shared__ __align__(16) unsigned short sBh[BN * 32];
    __shared__ __align__(16) unsigned short sBl[BN * 32];

    const int tid = threadIdx.x;
    const int w = tid >> 6, lane = tid & 63;
    const int l15 = lane & 15, quad = lane >> 4;
    const int wm = w / WN, wn = w % WN;

    const int lin = blockIdx.x;
    const int msuper = lin / (8 * nTiles);
    const int rem = lin % (8 * nTiles);
    const int m0 = (msuper * 8 + (rem & 7)) * BM;
    const int n0 = (rem >> 3) * BN;

    const int ch = (lane & 3) ^ ((lane >> 3) & 3);       // staging swizzle
    const int sw = (quad ^ ((l15 >> 1) & 3)) * 8;        // frag-read swizzle

    const unsigned short* aG[NA];
    const unsigned short* bG[NB];
#pragma unroll
    for (int i = 0; i < NA; ++i)
        aG[i] = Ax + (size_t)(m0 + (w * NA + i) * 16 + (lane >> 2)) * 2048
                   + ch * 8;
#pragma unroll
    for (int i = 0; i < NB; ++i)
        bG[i] = Bt + (size_t)(n0 + (w * NB + i) * 16 + (lane >> 2)) * 2048
                   + ch * 8;

    floatx4 acc[FM][FN];
#pragma unroll
    for (int fm = 0; fm < FM; ++fm)
#pragma unroll
        for (int fn = 0; fn < FN; ++fn) acc[fm][fn] = (floatx4)0.f;

    for (int ks = 0; ks < 32; ++ks) {
        const int ko = ks * 32;          // hi at ko, lo at 1024+ko
        __syncthreads();
#pragma unroll
        for (int i = 0; i < NA; ++i) {
            GLD_LDS16(aG[i] + ko,        sAh + (w * NA + i) * 512);
            GLD_LDS16(aG[i] + 1024 + ko, sAl + (w * NA + i) * 512);
        }
#pragma unroll
        for (int i = 0; i < NB; ++i) {
            GLD_LDS16(bG[i] + ko,        sBh + (w * NB + i) * 512);
            GLD_LDS16(bG[i] + 1024 + ko, sBl + (w * NB + i) * 512);
        }
        __syncthreads();

        short8 ah[FM], al[FM], bh[FN], bl[FN];
#pragma unroll
        for (int fm = 0; fm < FM; ++fm) {
            const int off = ((wm * FM + fm) * 16 + l15) * 32 + sw;
            ah[fm] = *(const short8*)&sAh[off];
            al[fm] = *(const short8*)&sAl[off];
        }
#pragma unroll
        for (int fn = 0; fn < FN; ++fn) {
            const int off = ((wn * FN + fn) * 16 + l15) * 32 + sw;
            bh[fn] = *(const short8*)&sBh[off];
            bl[fn] = *(const short8*)&sBl[off];
        }
#pragma unroll
        for (int fm = 0; fm < FM; ++fm)
#pragma unroll
            for (int fn = 0; fn < FN; ++fn) {
                floatx4 a = acc[fm][fn];
                a = BMFMA(ah[fm], bh[fn], a);
                a = BMFMA(ah[fm], bl[fn], a);
                a = BMFMA(al[fm], bh[fn], a);
                acc[fm][fn] = a;
            }
    }

#pragma unroll
    for (int fm = 0; fm < FM; ++fm)
#pragma unroll
        for (int fn = 0; fn < FN; ++fn) {
            int col = n0 + (wn * FN + fn) * 16 + l15;
            float bv = bias[col];
#pragma unroll
            for (int r = 0; r < 4; ++r) {
                int row = m0 + (wm * FM + fm) * 16 + quad * 4 + r;
                C[(size_t)row * ldc + col] = acc[fm][fn][r] + bv;
            }
        }
}

// ---------------------------------------------------------------------------
// Single-precision bf16 MFMA GEMM. BK=64, runtime A/B/C strides.
// Used for: V-columns of the QKV projection and the out-projection.
// ---------------------------------------------------------------------------
template<int WM, int WN, int FM, int FN>
__global__ __launch_bounds__(256) void gemm_mfma_s(
    const unsigned short* __restrict__ A, int lda,
    const unsigned short* __restrict__ Bt, int ldb,
    const float* __restrict__ bias, float* __restrict__ C, int ldc, int nTiles)
{
    constexpr int BM = WM * FM * 16;
    constexpr int BN = WN * FN * 16;
    constexpr int NA = BM / 64;
    constexpr int NB = BN / 64;

    __shared__ __align__(16) unsigned short sA0[BM * 32];
    __shared__ __align__(16) unsigned short sA1[BM * 32];
    __shared__ __align__(16) unsigned short sB0[BN * 32];
    __shared__ __align__(16) unsigned short sB1[BN * 32];

    const int tid = threadIdx.x;
    const int w = tid >> 6, lane = tid & 63;
    const int l15 = lane & 15, quad = lane >> 4;
    const int wm = w / WN, wn = w % WN;

    const int lin = blockIdx.x;
    const int msuper = lin / (8 * nTiles);
    const int rem = lin % (8 * nTiles);
    const int m0 = (msuper * 8 + (rem & 7)) * BM;
    const int n0 = (rem >> 3) * BN;

    const int ch = (lane & 3) ^ ((lane >> 3) & 3);
    const int sw = (quad ^ ((l15 >> 1) & 3)) * 8;

    const unsigned short* aG[NA];
    const unsigned short* bG[NB];
#pragma unroll
    for (int i = 0; i < NA; ++i)
        aG[i] = A + (size_t)(m0 + (w * NA + i) * 16 + (lane >> 2)) * lda + ch * 8;
#pragma unroll
    for (int i = 0; i < NB; ++i)
        bG[i] = Bt + (size_t)(n0 + (w * NB + i) * 16 + (lane >> 2)) * ldb + ch * 8;

    floatx4 acc[FM][FN];
#pragma unroll
    for (int fm = 0; fm < FM; ++fm)
#pragma unroll
        for (int fn = 0; fn < FN; ++fn) acc[fm][fn] = (floatx4)0.f;

    for (int ks = 0; ks < 16; ++ks) {
        const int ko = ks * 64;
        __syncthreads();
#pragma unroll
        for (int i = 0; i < NA; ++i) {
            GLD_LDS16(aG[i] + ko,      sA0 + (w * NA + i) * 512);
            GLD_LDS16(aG[i] + ko + 32, sA1 + (w * NA + i) * 512);
        }
#pragma unroll
        for (int i = 0; i < NB; ++i) {
            GLD_LDS16(bG[i] + ko,      sB0 + (w * NB + i) * 512);
            GLD_LDS16(bG[i] + ko + 32, sB1 + (w * NB + i) * 512);
        }
        __syncthreads();

        short8 a0[FM], a1[FM], b0[FN], b1[FN];
#pragma unroll
        for (int fm = 0; fm < FM; ++fm) {
            const int off = ((wm * FM + fm) * 16 + l15) * 32 + sw;
            a0[fm] = *(const short8*)&sA0[off];
            a1[fm] = *(const short8*)&sA1[off];
        }
#pragma unroll
        for (int fn = 0; fn < FN; ++fn) {
            const int off = ((wn * FN + fn) * 16 + l15) * 32 + sw;
            b0[fn] = *(const short8*)&sB0[off];
            b1[fn] = *(const short8*)&sB1[off];
        }
#pragma unroll
        for (int fm = 0; fm < FM; ++fm)
#pragma unroll
            for (int fn = 0; fn < FN; ++fn) {
                floatx4 a = acc[fm][fn];
                a = BMFMA(a0[fm], b0[fn], a);
                a = BMFMA(a1[fm], b1[fn], a);
                acc[fm][fn] = a;
            }
    }

#pragma unroll
    for (int fm = 0; fm < FM; ++fm)
#pragma unroll
        for (int fn = 0; fn < FN; ++fn) {
            int col = n0 + (wn * FN + fn) * 16 + l15;
            float bv = bias[col];
#pragma unroll
            for (int r = 0; r < 4; ++r) {
                int row = m0 + (wm * FM + fm) * 16 + quad * 4 + r;
                C[(size_t)row * ldc + col] = acc[fm][fn][r] + bv;
            }
        }
}

// ---------------------------------------------------------------------------
// prep_qkv: RoPE + 1/8 q-scale + bf16 split. R10: Ql dropped (flash QK x2),
// Vl dropped (R9). Q hi / K hi+lo [bh][t][64]; V hi [bh][d][2048] transposed.
// ---------------------------------------------------------------------------
__global__ __launch_bounds__(256) void prep_qkv(
    const float* __restrict__ qkv,
    unsigned short* __restrict__ Qh,
    unsigned short* __restrict__ Kh, unsigned short* __restrict__ Kl,
    unsigned short* __restrict__ Vh)
{
    __shared__ float vt[64][65];
    const int tid = threadIdx.x;
    const int lin = blockIdx.x;
    const int tt = lin & 31, bh = lin >> 5;
    const int b = bh >> 4, h = bh & 15;
    const int r = tid >> 2;
    const int dblk = (tid & 3) * 16;
    const int tg = tt * 64 + r;
    const size_t src = (size_t)(b * SEQ + tg) * 3072 + h * 64 + dblk;
    const size_t dst = ((size_t)bh * SEQ + tg) * 64 + dblk;

    float q[16], k[16], v[16];
#pragma unroll
    for (int i = 0; i < 4; ++i) {
        *(float4*)&q[4 * i] = *(const float4*)(qkv + src + 4 * i);
        *(float4*)&k[4 * i] = *(const float4*)(qkv + src + 1024 + 4 * i);
        *(float4*)&v[4 * i] = *(const float4*)(qkv + src + 2048 + 4 * i);
    }
#pragma unroll
    for (int j = 0; j < 16; j += 2) {
        int pr = (dblk + j) >> 1;
        double e = (double)(2 * pr) / 64.0;
        float inv = (float)exp2(-e * 13.287712379549449);
        float ang = (float)tg * inv;
        float s, c;
        __sincosf(ang, &s, &c);
        float qe = q[j], qo = q[j + 1];
        q[j] = qe * c - qo * s; q[j + 1] = qe * s + qo * c;
        float ke = k[j], ko = k[j + 1];
        k[j] = ke * c - ko * s; k[j + 1] = ke * s + ko * c;
    }
    uint32_t ph[8], pl[8];
#pragma unroll
    for (int j = 0; j < 8; ++j) {
        float f0 = q[2 * j] * 0.125f, f1 = q[2 * j + 1] * 0.125f;
        ph[j] = (uint32_t)f2bf(f0) | ((uint32_t)f2bf(f1) << 16);
    }
    *(uint4*)(Qh + dst) = *(uint4*)&ph[0]; *(uint4*)(Qh + dst + 8) = *(uint4*)&ph[4];
#pragma unroll
    for (int j = 0; j < 8; ++j) {
        float f0 = k[2 * j], f1 = k[2 * j + 1];
        unsigned short h0 = f2bf(f0), h1 = f2bf(f1);
        ph[j] = (uint32_t)h0 | ((uint32_t)h1 << 16);
        pl[j] = (uint32_t)f2bf(f0 - bf2f(h0)) | ((uint32_t)f2bf(f1 - bf2f(h1)) << 16);
    }
    *(uint4*)(Kh + dst) = *(uint4*)&ph[0]; *(uint4*)(Kh + dst + 8) = *(uint4*)&ph[4];
    *(uint4*)(Kl + dst) = *(uint4*)&pl[0]; *(uint4*)(Kl + dst + 8) = *(uint4*)&pl[4];

#pragma unroll
    for (int j = 0; j < 16; ++j) vt[r][dblk + j] = v[j];
    __syncthreads();
    const int d2 = tid >> 2;
    const int tb = (tid & 3) * 16;
#pragma unroll
    for (int j = 0; j < 8; ++j) {
        float f0 = vt[tb + 2 * j][d2], f1 = vt[tb + 2 * j + 1][d2];
        ph[j] = (uint32_t)f2bf(f0) | ((uint32_t)f2bf(f1) << 16);
    }
    const size_t vdst = ((size_t)bh * 64 + d2) * SEQ + tt * 64 + tb;
    *(uint4*)(Vh + vdst) = *(uint4*)&ph[0]; *(uint4*)(Vh + vdst + 8) = *(uint4*)&ph[4];
}

// ---------------------------------------------------------------------------
// MFMA flash attention, R10: QK^T x2 = Qh*(Kh+Kl) (Ql term dropped — below
// the bf16-ULP noise floor per R9 evidence). 26 MFMA/iter, 6 DMA loads/iter,
// LDS 32KB, 1024 blocks heavy-first. attnx plain bf16 [tok][1024].
// ---------------------------------------------------------------------------
__global__ __launch_bounds__(256, 4) void flash_mfma(
    const unsigned short* __restrict__ Qh,
    const unsigned short* __restrict__ Kh, const unsigned short* __restrict__ Kl,
    const unsigned short* __restrict__ Vh,
    const int* __restrict__ am, unsigned short* __restrict__ attnx)
{
    __shared__ __align__(16) unsigned short sKh[4096];
    __shared__ __align__(16) unsigned short sKl[4096];
    __shared__ __align__(16) unsigned short sVh[4096];
    __shared__ __align__(16) unsigned short sP[4096];

    const int tid = threadIdx.x;
    const int lane = tid & 63, w = tid >> 6;
    const int l15 = lane & 15, quad = lane >> 4;
    const int lin = blockIdx.x;
    const int bh = lin & 31;
    const int qt = 31 - (lin >> 5);            // heavy q-tiles dispatched first
    const int b = bh >> 4, h = bh & 15;
    const int sw = (quad ^ ((l15 >> 1) & 3)) * 8;
    const int ch = (lane & 3) ^ ((lane >> 3) & 3);
    unsigned short* pbase = sP + w * 1024;

    short8 ones;
#pragma unroll
    for (int j = 0; j < 8; ++j) ones[j] = (short)0x3F80;  // bf16 1.0

    const size_t qb = ((size_t)bh * SEQ + qt * 64 + w * 16 + l15) * 64 + quad * 8;
    const short8 qh0 = *(const short8*)(Qh + qb);
    const short8 qh1 = *(const short8*)(Qh + qb + 32);

    const size_t kRow0 = ((size_t)bh * SEQ + w * 16 + (lane >> 2)) * 64 + ch * 8;
    const size_t vRow  = ((size_t)bh * 64 + w * 16 + (lane >> 2)) * SEQ + ch * 8;

    floatx4 O[4];
    floatx4 lAcc = (floatx4)0.f;
#pragma unroll
    for (int nf = 0; nf < 4; ++nf) O[nf] = (floatx4)0.f;

    const int mg = qt * 64 + w * 16 + l15;

    for (int kt = 0; kt <= qt; ++kt) {
        __syncthreads();
        {
            const size_t kg = kRow0 + (size_t)kt * 64 * 64;
            const size_t vg = vRow + kt * 64;
            GLD_LDS16(Kh + kg,      sKh + w * 512);
            GLD_LDS16(Kh + kg + 32, sKh + 2048 + w * 512);
            GLD_LDS16(Kl + kg,      sKl + w * 512);
            GLD_LDS16(Kl + kg + 32, sKl + 2048 + w * 512);
            GLD_LDS16(Vh + vg,      sVh + w * 512);
            GLD_LDS16(Vh + vg + 32, sVh + 2048 + w * 512);
        }
        __syncthreads();

        const bool diag = (kt == qt);

        // ---- S^T = K Q^T (x2), exp, pack, stage P (wave-private) ----
#pragma unroll
        for (int nf = 0; nf < 4; ++nf) {
            const int base = (nf * 16 + l15) * 32 + sw;
            const short8 kh0 = *(const short8*)&sKh[base];
            const short8 kh1 = *(const short8*)&sKh[2048 + base];
            const short8 kl0 = *(const short8*)&sKl[base];
            const short8 kl1 = *(const short8*)&sKl[2048 + base];
            floatx4 s = (floatx4)0.f;
            s = BMFMA(kh0, qh0, s);
            s = BMFMA(kh1, qh1, s);
            s = BMFMA(kl0, qh0, s);
            s = BMFMA(kl1, qh1, s);

            const int tb = kt * 64 + nf * 16 + quad * 4;
            const int4 amv = *(const int4*)(am + b * SEQ + tb);
            float pv[4];
#pragma unroll
            for (int r = 0; r < 4; ++r) {
                bool ok = ((const int*)&amv)[r] != 0;
                if (diag) ok = ok && (tb + r <= mg);
                pv[r] = ok ? __expf(s[r] - 16.0f) : 0.0f;
            }
            ushort4 pk;
            pk.x = f2bf(pv[0]); pk.y = f2bf(pv[1]);
            pk.z = f2bf(pv[2]); pk.w = f2bf(pv[3]);
            const int pos = (((nf & 1) * 2 + (quad >> 1)) ^ ((l15 >> 1) & 3));
            *(ushort4*)(pbase + (nf >> 1) * 512 + l15 * 32 + pos * 8
                        + (quad & 1) * 4) = pk;
        }

        const short8 pf0 = *(const short8*)(pbase + l15 * 32 + sw);
        const short8 pf1 = *(const short8*)(pbase + 512 + l15 * 32 + sw);

        // ---- l += P @ ones ; O += P @ Vh ----
        lAcc = BMFMA(pf0, ones, lAcc);
        lAcc = BMFMA(pf1, ones, lAcc);
#pragma unroll
        for (int nf = 0; nf < 4; ++nf) {
            const int vb = (nf * 16 + l15) * 32 + sw;
            floatx4 o = O[nf];
            o = BMFMA(pf0, *(const short8*)&sVh[vb], o);
            o = BMFMA(pf1, *(const short8*)&sVh[2048 + vb], o);
            O[nf] = o;
        }
    }

    // ---- finalize: divide by l, store plain bf16 ----
    float rl[4];
#pragma unroll
    for (int r = 0; r < 4; ++r) rl[r] = 1.0f / lAcc[r];
#pragma unroll
    for (int nf = 0; nf < 4; ++nf)
#pragma unroll
        for (int r = 0; r < 4; ++r) {
            const int tok = b * SEQ + qt * 64 + w * 16 + quad * 4 + r;
            const int col = h * 64 + nf * 16 + l15;
            attnx[(size_t)tok * 1024 + col] = f2bf(O[nf][r] * rl[r]);
        }
}

// ---------------------------------------------------------------------------
extern "C" void kernel_launch(void* const* d_in, const int* in_sizes, int n_in,
                              void* d_out, int out_size, void* d_ws, size_t ws_size,
                              hipStream_t stream)
{
    const float* x    = (const float*)d_in[0];
    const int*   am   = (const int*)d_in[1];
    const float* Wqkv = (const float*)d_in[2];
    const float* bqkv = (const float*)d_in[3];
    const float* Wout = (const float*)d_in[4];
    const float* bout = (const float*)d_in[5];
    float* out = (float*)d_out;

    // ws layout (113.2 MB, unchanged footprint):
    //   Bt 12.58MB | qkv fp32 50.33MB (start reused as attnx bf16 after prep) |
    //   Qh Ql(unused) Kh Kl Vh slots 8.39MB each; Ax aliases Vh+VlSlot pre-prep
    char* ws = (char*)d_ws;
    unsigned short* Bt = (unsigned short*)ws;
    float* qkv = (float*)(ws + 12582912);
    unsigned short* attnx = (unsigned short*)qkv;        // alias: qkv dead after prep
    unsigned short* Qh = (unsigned short*)(ws + 62914560);
    unsigned short* Kh = Qh + 2 * 4194304;               // Ql slot left unused
    unsigned short* Kl = Kh + 4194304;
    unsigned short* Vh = Kl + 4194304;
    unsigned short* Ax = Vh;                             // alias: dead after gemm1

    // 0) split x -> Ax (hi|lo) and W_qkv -> Bt, one launch
    split_inputs<<<7168, 256, 0, stream>>>(x, Wqkv, Ax, Bt);

    // 1a) qkv[:, 0:2048] (Q,K cols) = x @ Wqkv + b   (fused-x3, fp32-grade)
    gemm_mfma_x3f<2, 2, 4, 4><<<512, 256, 0, stream>>>(
        Ax, Bt, bqkv, qkv, 3072, 16);
    // 1b) qkv[:, 2048:3072] (V cols) = x @ Wqkv + b  (single bf16 — V is
    //     truncated to bf16 in flash anyway)
    gemm_mfma_s<2, 2, 4, 4><<<256, 256, 0, stream>>>(
        Ax, 2048, Bt + (size_t)2048 * 2048, 2048,
        bqkv + 2048, qkv + 2048, 3072, 8);

    // 2) RoPE + scale + split (Q hi, K hi+lo, V hi transposed)
    prep_qkv<<<1024, 256, 0, stream>>>(qkv, Qh, Kh, Kl, Vh);

    // 3) MFMA flash attention -> attnx (plain bf16)
    flash_mfma<<<1024, 256, 0, stream>>>(Qh, Kh, Kl, Vh, am, attnx);

    // 4) out = attn @ W_out + b  (single bf16, 128^2 tiles)
    split_w_t<<<dim3(32, 32), 256, 0, stream>>>(Wout, 1024, Bt);
    gemm_mfma_s<2, 2, 4, 4><<<256, 256, 0, stream>>>(
        attnx, 1024, Bt, 2048, bout, out, 1024, 8);
}